// Round 1
// baseline (234.668 us; speedup 1.0000x reference)
//
#include <hip/hip_runtime.h>
#include <cstdint>

#define TOPK_K 10
#define NCLS   80
#define EPS_F     1e-8f
#define IOU_EPS_F 1e-7f

// ---------------------------------------------------------------------------
// k_prep: detect gt_mask dtype (bool/u8 vs int32) and expand to int gmask[B*M].
// An int32 0/1 buffer has every byte at (i%4!=0) == 0 within the first n bytes;
// a bool buffer (~80% ones) has many nonzero bytes there. Deterministic per input.
// ---------------------------------------------------------------------------
__global__ void k_prep(const unsigned char* __restrict__ gm, int n,
                       int* __restrict__ gmask)
{
    __shared__ int anynz;
    if (threadIdx.x == 0) anynz = 0;
    __syncthreads();
    for (int i = threadIdx.x; i < n; i += blockDim.x) {
        if ((i & 3) && gm[i]) anynz = 1;   // benign race, all write 1
    }
    __syncthreads();
    const int is_int32 = (anynz == 0);
    const int* gi = (const int*)gm;
    for (int i = threadIdx.x; i < n; i += blockDim.x) {
        gmask[i] = is_int32 ? (gi[i] != 0) : (gm[i] != 0);
    }
}

// ---------------------------------------------------------------------------
// k_topk: one block per (b,m). Compute align over all anchors, select top-10
// with jax.lax.top_k tie-breaking (value desc, index asc), set bit m in the
// per-anchor GT bitmask for selected anchors that pass in_gt (gtm known true).
// ---------------------------------------------------------------------------
__global__ __launch_bounds__(256) void k_topk(
    const float*  __restrict__ ps,    // (B,A,C)
    const float4* __restrict__ pb,    // (B,A,4)
    const float2* __restrict__ apts,  // (A,2)
    const int*    __restrict__ gl,    // (B,M)
    const float4* __restrict__ gb,    // (B,M,4)
    const int*    __restrict__ gmask, // (B,M)
    unsigned long long* __restrict__ mask_bits, // (B,A)
    int B, int A, int C, int M)
{
    const int bm = blockIdx.x;
    if (!gmask[bm]) return;
    const int b = bm / M;
    const int m = bm - b * M;

    const float4 g = gb[bm];
    const float gx0 = g.x, gy0 = g.y, gx1 = g.z, gy1 = g.w;
    const float areag = (gx1 - gx0) * (gy1 - gy0);
    const int cls = gl[bm];
    const float*  psb = ps + (size_t)b * A * C + cls;
    const float4* pbb = pb + (size_t)b * A;

    // per-thread top-10 (sorted desc by (value, -index)); static indices only
    float tv[TOPK_K]; int ti[TOPK_K];
#pragma unroll
    for (int i = 0; i < TOPK_K; ++i) { tv[i] = -1.0f; ti[i] = 0x7fffffff; }

    for (int a = threadIdx.x; a < A; a += blockDim.x) {
        const float2 an = apts[a];
        const float d = fminf(fminf(an.x - gx0, an.y - gy0),
                              fminf(gx1 - an.x, gy1 - an.y));
        float al = 0.0f;
        if (d > EPS_F) {
            const float4 p = pbb[a];
            const float iw = fmaxf(fminf(gx1, p.z) - fmaxf(gx0, p.x), 0.0f);
            const float ih = fmaxf(fminf(gy1, p.w) - fmaxf(gy0, p.y), 0.0f);
            const float inter = iw * ih;
            const float areap = (p.z - p.x) * (p.w - p.y);
            const float iou = fmaxf(inter / (areag + areap - inter + IOU_EPS_F), 0.0f);
            const float sc = psb[(size_t)a * C];
            const float i2 = iou * iou;
            al = sc * (i2 * i2 * i2);  // score^1 * iou^6, x4*x2 assoc like XLA
        }
        // bubble-insert (fully unrolled, compile-time indices -> registers)
        if ((al > tv[TOPK_K - 1]) ||
            (al == tv[TOPK_K - 1] && a < ti[TOPK_K - 1])) {
            float cv = al; int ci = a;
#pragma unroll
            for (int q = 0; q < TOPK_K; ++q) {
                const bool bet = (cv > tv[q]) || (cv == tv[q] && ci < ti[q]);
                if (bet) {
                    const float tv_ = tv[q]; const int ti_ = ti[q];
                    tv[q] = cv; ti[q] = ci; cv = tv_; ci = ti_;
                }
            }
        }
    }

    // block-wide selection: 10 rounds of argmax with tie-break (idx asc)
    __shared__ float sv[256];
    __shared__ int   si[256];
    const unsigned long long bit = 1ull << m;
    int p = 0;
    for (int r = 0; r < TOPK_K; ++r) {
        sv[threadIdx.x] = (p < TOPK_K) ? tv[p] : -1.0f;
        si[threadIdx.x] = (p < TOPK_K) ? ti[p] : 0x7fffffff;
        const int myci = si[threadIdx.x];
        __syncthreads();
        for (int s = 128; s > 0; s >>= 1) {
            if (threadIdx.x < s) {
                const float ov = sv[threadIdx.x + s];
                const int   oi = si[threadIdx.x + s];
                if ((ov > sv[threadIdx.x]) ||
                    (ov == sv[threadIdx.x] && oi < si[threadIdx.x])) {
                    sv[threadIdx.x] = ov; si[threadIdx.x] = oi;
                }
            }
            __syncthreads();
        }
        const int widx = si[0];
        if (threadIdx.x == 0 && widx != 0x7fffffff) {
            const float2 an = apts[widx];
            const float d = fminf(fminf(an.x - gx0, an.y - gy0),
                                  fminf(gx1 - an.x, gy1 - an.y));
            if (d > EPS_F)
                atomicOr(&mask_bits[(size_t)b * A + widx], bit);
        }
        if (myci == widx) ++p;   // unique winner pops its candidate
        __syncthreads();
    }
}

// ---------------------------------------------------------------------------
// k_resolve: per anchor — fg count, multi-assignment resolution via argmax IoU,
// per-GT pos_align/pos_iou atomics, labels/boxes/fg outputs.
// ---------------------------------------------------------------------------
__global__ __launch_bounds__(256) void k_resolve(
    const float*  __restrict__ ps,
    const float4* __restrict__ pb,
    const float2* __restrict__ apts,
    const int*    __restrict__ gl,
    const float4* __restrict__ gb,
    const int*    __restrict__ gmask,
    const unsigned long long* __restrict__ mask_bits,
    int*          __restrict__ assign,
    float*        __restrict__ aval,
    unsigned int* __restrict__ pos_align,
    unsigned int* __restrict__ pos_iou,
    float*        __restrict__ out,
    int B, int A, int C, int M)
{
    const int id = blockIdx.x * blockDim.x + threadIdx.x;
    if (id >= B * A) return;
    const int b = id / A;
    const int a = id - b * A;

    const unsigned long long bits = mask_bits[id];
    const int cnt = __popcll(bits);
    int t = 0, fg = 0;
    const float2 an = apts[a];
    const float4 p  = pb[id];
    const float areap = (p.z - p.x) * (p.w - p.y);

    if (cnt == 1) {
        t = __ffsll(bits) - 1; fg = 1;
    } else if (cnt > 1) {
        // jnp.argmax over valid-masked ious (first occurrence of max)
        float best = -1.0f; int bi = 0;
        for (int mm = 0; mm < M; ++mm) {
            const float4 gg = gb[b * M + mm];
            const float d = fminf(fminf(an.x - gg.x, an.y - gg.y),
                                  fminf(gg.z - an.x, gg.w - an.y));
            float iou = 0.0f;
            if (d > EPS_F && gmask[b * M + mm]) {
                const float iw = fmaxf(fminf(gg.z, p.z) - fmaxf(gg.x, p.x), 0.0f);
                const float ih = fmaxf(fminf(gg.w, p.w) - fmaxf(gg.y, p.y), 0.0f);
                const float inter = iw * ih;
                const float areag = (gg.z - gg.x) * (gg.w - gg.y);
                iou = fmaxf(inter / (areag + areap - inter + IOU_EPS_F), 0.0f);
            }
            if (iou > best) { best = iou; bi = mm; }
        }
        t = bi; fg = 1;
    }

    float av = 0.0f;
    if (fg) {
        const float4 gg = gb[b * M + t];
        const float d = fminf(fminf(an.x - gg.x, an.y - gg.y),
                              fminf(gg.z - an.x, gg.w - an.y));
        if (d > EPS_F && gmask[b * M + t]) {
            const float iw = fmaxf(fminf(gg.z, p.z) - fmaxf(gg.x, p.x), 0.0f);
            const float ih = fmaxf(fminf(gg.w, p.w) - fmaxf(gg.y, p.y), 0.0f);
            const float inter = iw * ih;
            const float areag = (gg.z - gg.x) * (gg.w - gg.y);
            const float iou = fmaxf(inter / (areag + areap - inter + IOU_EPS_F), 0.0f);
            const float sc = ps[((size_t)b * A + a) * C + gl[b * M + t]];
            const float i2 = iou * iou;
            av = sc * (i2 * i2 * i2);
            // values >= 0 -> uint compare == float compare
            atomicMax(&pos_align[b * M + t], __float_as_uint(av));
            atomicMax(&pos_iou[b * M + t],  __float_as_uint(iou));
        }
    }

    assign[id] = t;
    aval[id]   = av;

    int lab = gl[b * M + t];
    lab = lab < 0 ? 0 : (lab > NCLS ? NCLS : lab);
    out[id] = (float)lab;                                   // target_labels
    ((float4*)(out + (size_t)B * A))[id] = gb[b * M + t];   // target_boxes
    out[(size_t)B * A * (5 + C) + id] = fg ? 1.0f : 0.0f;   // fg mask
}

// ---------------------------------------------------------------------------
// k_norm: norm[b,a] = aval * pos_iou[t] / (pos_align[t] + EPS); aval==0 when
// unassigned, so no fg gate needed.
// ---------------------------------------------------------------------------
__global__ void k_norm(const int* __restrict__ assign,
                       const float* __restrict__ aval,
                       const unsigned int* __restrict__ pos_align,
                       const unsigned int* __restrict__ pos_iou,
                       float* __restrict__ normv, int BA, int A, int M)
{
    const int id = blockIdx.x * blockDim.x + threadIdx.x;
    if (id >= BA) return;
    const int b = id / A;
    const int t = assign[id];
    const float pa = __uint_as_float(pos_align[b * M + t]);
    const float pi = __uint_as_float(pos_iou[b * M + t]);
    normv[id] = aval[id] * pi / (pa + EPS_F);
}

// ---------------------------------------------------------------------------
// k_scores: coalesced float4 one-hot * norm write of (B,A,C).
// ---------------------------------------------------------------------------
__global__ void k_scores(const float* __restrict__ labels,
                         const float* __restrict__ normv,
                         float4* __restrict__ scores, int BA, int C4)
{
    const int gid = blockIdx.x * blockDim.x + threadIdx.x;
    if (gid >= BA * C4) return;
    const int row = gid / C4;
    const int c4  = gid - row * C4;
    const int lab = (int)labels[row];
    const float nv = normv[row];
    const int cb = c4 * 4;
    float4 v;
    v.x = (cb + 0 == lab) ? nv : 0.0f;
    v.y = (cb + 1 == lab) ? nv : 0.0f;
    v.z = (cb + 2 == lab) ? nv : 0.0f;
    v.w = (cb + 3 == lab) ? nv : 0.0f;
    scores[gid] = v;
}

extern "C" void kernel_launch(void* const* d_in, const int* in_sizes, int n_in,
                              void* d_out, int out_size, void* d_ws, size_t ws_size,
                              hipStream_t stream)
{
    const float*  ps = (const float*)d_in[0];
    const float4* pb = (const float4*)d_in[1];
    const float2* ap = (const float2*)d_in[2];
    const int*    gl = (const int*)d_in[3];
    const float4* gb = (const float4*)d_in[4];
    const unsigned char* gm = (const unsigned char*)d_in[5];

    const int A = in_sizes[2] / 2;
    const int B = in_sizes[1] / (A * 4);
    const int M = in_sizes[4] / (B * 4);
    const int C = in_sizes[0] / (B * A);
    const int BA = B * A;

    // workspace layout (256B-aligned chunks)
    size_t off = 0;
    auto alloc = [&](size_t bytes) {
        void* p = (char*)d_ws + off;
        off += (bytes + 255) & ~(size_t)255;
        return p;
    };
    unsigned long long* mask_bits = (unsigned long long*)alloc((size_t)BA * 8);
    unsigned int* pos_a = (unsigned int*)alloc((size_t)B * M * 4);
    unsigned int* pos_i = (unsigned int*)alloc((size_t)B * M * 4);
    const size_t zero_bytes = off;                 // mask_bits + pos arrays
    int*   gmask  = (int*)alloc((size_t)B * M * 4);
    int*   assign = (int*)alloc((size_t)BA * 4);
    float* aval   = (float*)alloc((size_t)BA * 4);
    float* normv  = (float*)alloc((size_t)BA * 4);

    hipMemsetAsync(d_ws, 0, zero_bytes, stream);

    k_prep<<<1, 256, 0, stream>>>(gm, B * M, gmask);

    k_topk<<<B * M, 256, 0, stream>>>(ps, pb, ap, gl, gb, gmask, mask_bits,
                                      B, A, C, M);

    float* out = (float*)d_out;
    k_resolve<<<(BA + 255) / 256, 256, 0, stream>>>(
        ps, pb, ap, gl, gb, gmask, mask_bits,
        assign, aval, pos_a, pos_i, out, B, A, C, M);

    k_norm<<<(BA + 255) / 256, 256, 0, stream>>>(assign, aval, pos_a, pos_i,
                                                 normv, BA, A, M);

    const int C4 = C / 4;
    const int tot = BA * C4;
    k_scores<<<(tot + 255) / 256, 256, 0, stream>>>(
        out, normv, (float4*)(out + (size_t)BA * 5), BA, C4);
}